// Round 9
// baseline (446.511 us; speedup 1.0000x reference)
//
#include <hip/hip_runtime.h>
#include <hip/hip_bf16.h>

#define NN 50000
#define EE 800000
#define ET (EE + NN)
#define F_IN 128
#define HID 32
#define H1 4
#define H2 8
#define E_DEC 100000
#define NEG_SLOPE 0.2f

typedef __attribute__((ext_vector_type(8))) short short8;
typedef __attribute__((ext_vector_type(4))) float floatx4;

__device__ __forceinline__ unsigned short f2b(float f) {
    __hip_bfloat16 h = __float2bfloat16(f);
    return *reinterpret_cast<unsigned short*>(&h);
}
__device__ __forceinline__ float b2f(unsigned short u) {
    return __uint_as_float(((unsigned int)u) << 16);
}

// ---------------- fill counts with 1 (self-loop pre-counted) ----------------
__global__ void fillone_k(int* __restrict__ p, int n) {
    int i = blockIdx.x * blockDim.x + threadIdx.x;
    if (i < n) p[i] = 1;
}

// ---------------- CSR build: histogram of dst (real edges only, int4) ----------------
__global__ void hist_k(const int* __restrict__ ei, int* __restrict__ counts) {
    int t = blockIdx.x * blockDim.x + threadIdx.x;
    if (t >= EE / 4) return;
    const int4 d4 = ((const int4*)(ei + EE))[t];
    atomicAdd(&counts[d4.x], 1);
    atomicAdd(&counts[d4.y], 1);
    atomicAdd(&counts[d4.z], 1);
    atomicAdd(&counts[d4.w], 1);
}

// ---------------- single-block chunked exclusive scan over counts[NN] ----------------
__global__ void scanall_k(const int* __restrict__ counts, int* __restrict__ start,
                          int* __restrict__ cursor) {
    __shared__ int sh[1024];
    __shared__ int base;
    const int t = threadIdx.x;
    if (t == 0) base = 0;
    __syncthreads();
    for (int c0 = 0; c0 < NN; c0 += 1024) {
        const int i = c0 + t;
        const int c = (i < NN) ? counts[i] : 0;
        sh[t] = c;
        __syncthreads();
        for (int off = 1; off < 1024; off <<= 1) {
            const int u = (t >= off) ? sh[t - off] : 0;
            __syncthreads();
            sh[t] += u;
            __syncthreads();
        }
        const int excl = base + sh[t] - c;
        if (i < NN) {
            start[i] = excl;
            cursor[i] = excl;
        }
        __syncthreads();
        if (t == 1023) base += sh[1023];
        __syncthreads();
    }
    if (t == 0) start[NN] = ET;
}

// ---------------- scatter: real edges (int4) + self-loops ----------------
__global__ void scatter_k(const int* __restrict__ ei, int* __restrict__ cursor,
                          int* __restrict__ csr) {
    const int NT_E = EE / 4;
    const int t = blockIdx.x * blockDim.x + threadIdx.x;
    if (t < NT_E) {
        const int4 s4 = ((const int4*)ei)[t];
        const int4 d4 = ((const int4*)(ei + EE))[t];
        csr[atomicAdd(&cursor[d4.x], 1)] = s4.x;
        csr[atomicAdd(&cursor[d4.y], 1)] = s4.y;
        csr[atomicAdd(&cursor[d4.z], 1)] = s4.z;
        csr[atomicAdd(&cursor[d4.w], 1)] = s4.w;
    } else {
        const int j = (t - NT_E) * 4;
#pragma unroll
        for (int k = 0; k < 4; ++k) {
            const int n = j + k;
            if (n < NN) csr[atomicAdd(&cursor[n], 1)] = n;
        }
    }
}

// ---------------- pack W into MFMA B-fragment layout ----------------
template <int OUT>
__global__ void packW_k(const float* __restrict__ W, unsigned short* __restrict__ Wp) {
    const int total = (OUT / 16) * 4 * 64;
    int id = blockIdx.x * 256 + threadIdx.x;
    if (id >= total) return;
    const int col = ((id >> 8) << 4) + (id & 15);
    const int k0 = ((id >> 6) & 3) * 32 + ((id >> 4) & 3) * 8;
    ushort4 lo, hi;
    lo.x = f2b(W[(k0 + 0) * OUT + col]);
    lo.y = f2b(W[(k0 + 1) * OUT + col]);
    lo.z = f2b(W[(k0 + 2) * OUT + col]);
    lo.w = f2b(W[(k0 + 3) * OUT + col]);
    hi.x = f2b(W[(k0 + 4) * OUT + col]);
    hi.y = f2b(W[(k0 + 5) * OUT + col]);
    hi.z = f2b(W[(k0 + 6) * OUT + col]);
    hi.w = f2b(W[(k0 + 7) * OUT + col]);
    ((ushort4*)Wp)[id * 2] = lo;
    ((ushort4*)Wp)[id * 2 + 1] = hi;
}

// ---------------- MFMA GEMM + fused al epilogue ----------------
template <int OUT, int H, int CT, bool F32IN>
__global__ void mfma_gemm_k(const void* __restrict__ Xin,
                            const unsigned short* __restrict__ Wp,
                            const float* __restrict__ a_src, const float* __restrict__ a_dst,
                            unsigned short* __restrict__ Hout,
                            float* __restrict__ als, float* __restrict__ ald) {
    const int wave = threadIdx.x >> 6;
    const int lane = threadIdx.x & 63;
    const int quad = lane >> 4;
    const int rl = lane & 15;
    const int r0 = blockIdx.x * 64;
    floatx4 acc[4][CT];
#pragma unroll
    for (int rt = 0; rt < 4; ++rt)
#pragma unroll
        for (int ct = 0; ct < CT; ++ct) acc[rt][ct] = {0.f, 0.f, 0.f, 0.f};

#pragma unroll
    for (int ks = 0; ks < 4; ++ks) {
        short8 a[4];
#pragma unroll
        for (int rt = 0; rt < 4; ++rt) {
            int row = r0 + rt * 16 + rl;
            row = row < NN ? row : NN - 1;
            if (F32IN) {
                const float4* xp =
                    (const float4*)((const float*)Xin + (long long)row * 128 + ks * 32 + quad * 8);
                const float4 v0 = xp[0];
                const float4 v1 = xp[1];
                short8 tt;
                tt[0] = (short)f2b(v0.x);
                tt[1] = (short)f2b(v0.y);
                tt[2] = (short)f2b(v0.z);
                tt[3] = (short)f2b(v0.w);
                tt[4] = (short)f2b(v1.x);
                tt[5] = (short)f2b(v1.y);
                tt[6] = (short)f2b(v1.z);
                tt[7] = (short)f2b(v1.w);
                a[rt] = tt;
            } else {
                a[rt] = *(const short8*)((const unsigned short*)Xin +
                                         (long long)row * 128 + ks * 32 + quad * 8);
            }
        }
#pragma unroll
        for (int ct = 0; ct < CT; ++ct) {
            const int ctg = wave * CT + ct;
            const short8 b = *(const short8*)(Wp + (((ctg * 4 + ks) * 64 + lane) << 3));
#pragma unroll
            for (int rt = 0; rt < 4; ++rt)
                acc[rt][ct] = __builtin_amdgcn_mfma_f32_16x16x32_bf16(a[rt], b, acc[rt][ct], 0, 0, 0);
        }
    }
    // ---- write h ----
#pragma unroll
    for (int rt = 0; rt < 4; ++rt) {
        const int rowbase = r0 + rt * 16 + quad * 4;
#pragma unroll
        for (int ct = 0; ct < CT; ++ct) {
            const int col = (wave * CT + ct) * 16 + rl;
#pragma unroll
            for (int r = 0; r < 4; ++r) {
                const int row = rowbase + r;
                if (row < NN) Hout[(long long)row * OUT + col] = f2b(acc[rt][ct][r]);
            }
        }
    }
    // ---- fused al ----
    float asv[CT], adv[CT];
#pragma unroll
    for (int ct = 0; ct < CT; ++ct) {
        const int col = (wave * CT + ct) * 16 + rl;
        asv[ct] = a_src[col];
        adv[ct] = a_dst[col];
    }
#pragma unroll
    for (int rt = 0; rt < 4; ++rt) {
#pragma unroll
        for (int r = 0; r < 4; ++r) {
            const int row = r0 + rt * 16 + quad * 4 + r;
            float ps[CT / 2], pd[CT / 2];
#pragma unroll
            for (int hh = 0; hh < CT / 2; ++hh) {
                ps[hh] = acc[rt][2 * hh][r] * asv[2 * hh] + acc[rt][2 * hh + 1][r] * asv[2 * hh + 1];
                pd[hh] = acc[rt][2 * hh][r] * adv[2 * hh] + acc[rt][2 * hh + 1][r] * adv[2 * hh + 1];
#pragma unroll
                for (int m = 8; m >= 1; m >>= 1) {
                    ps[hh] += __shfl_xor(ps[hh], m, 64);
                    pd[hh] += __shfl_xor(pd[hh], m, 64);
                }
            }
            if (rl == 0 && row < NN) {
#pragma unroll
                for (int hh = 0; hh < CT / 2; ++hh) {
                    const int hd = wave * (CT / 2) + hh;
                    als[row * H + hd] = ps[hh];
                    ald[row * H + hd] = pd[hh];
                }
            }
        }
    }
}

// ---------------- CSR gather: one wave per node, ushort4/lane, 8/4/1 unroll ----
template <int OUT, int H, bool RELU>
__global__ void gather_k(const int* __restrict__ start, const int* __restrict__ csr,
                         const float* __restrict__ als, const float* __restrict__ ald,
                         const unsigned short* __restrict__ Hin,
                         const float* __restrict__ bias, unsigned short* __restrict__ outp) {
    constexpr int LPR = OUT / 4;           // 64 (OUT=256) or 32 (OUT=128)
    constexpr int EPW = 64 / LPR;          // 1 or 2
    const int d = blockIdx.x;
    const int lane = threadIdx.x;          // blockDim = 64
    const int cl = lane & (LPR - 1);
    const int slot = lane >> (LPR == 64 ? 6 : 5);
    const int hd = cl >> 3;
    const int beg = start[d], end = start[d + 1];
    const float aldd = ald[d * H + hd];
    float a0 = 0.f, a1 = 0.f, a2 = 0.f, a3 = 0.f, den = 0.f;
    int i = beg + slot;
    for (; i + 7 * EPW < end; i += 8 * EPW) {
        int s[8];
        float l[8];
        ushort4 hv[8];
#pragma unroll
        for (int k = 0; k < 8; ++k) s[k] = csr[i + k * EPW];
#pragma unroll
        for (int k = 0; k < 8; ++k) l[k] = als[s[k] * H + hd] + aldd;
#pragma unroll
        for (int k = 0; k < 8; ++k) hv[k] = *(const ushort4*)(Hin + (long long)s[k] * OUT + cl * 4);
#pragma unroll
        for (int k = 0; k < 8; ++k) {
            float lg = l[k] > 0.f ? l[k] : NEG_SLOPE * l[k];
            const float w = __expf(lg);
            den += w;
            a0 += w * b2f(hv[k].x);
            a1 += w * b2f(hv[k].y);
            a2 += w * b2f(hv[k].z);
            a3 += w * b2f(hv[k].w);
        }
    }
    for (; i + 3 * EPW < end; i += 4 * EPW) {
        int s[4];
        float l[4];
        ushort4 hv[4];
#pragma unroll
        for (int k = 0; k < 4; ++k) s[k] = csr[i + k * EPW];
#pragma unroll
        for (int k = 0; k < 4; ++k) l[k] = als[s[k] * H + hd] + aldd;
#pragma unroll
        for (int k = 0; k < 4; ++k) hv[k] = *(const ushort4*)(Hin + (long long)s[k] * OUT + cl * 4);
#pragma unroll
        for (int k = 0; k < 4; ++k) {
            float lg = l[k] > 0.f ? l[k] : NEG_SLOPE * l[k];
            const float w = __expf(lg);
            den += w;
            a0 += w * b2f(hv[k].x);
            a1 += w * b2f(hv[k].y);
            a2 += w * b2f(hv[k].z);
            a3 += w * b2f(hv[k].w);
        }
    }
    for (; i < end; i += EPW) {
        const int s = csr[i];
        float lg = als[s * H + hd] + aldd;
        lg = lg > 0.f ? lg : NEG_SLOPE * lg;
        const float w = __expf(lg);
        const ushort4 hv = *(const ushort4*)(Hin + (long long)s * OUT + cl * 4);
        den += w;
        a0 += w * b2f(hv.x);
        a1 += w * b2f(hv.y);
        a2 += w * b2f(hv.z);
        a3 += w * b2f(hv.w);
    }
    if (EPW == 2) {
        a0 += __shfl_xor(a0, 32, 64);
        a1 += __shfl_xor(a1, 32, 64);
        a2 += __shfl_xor(a2, 32, 64);
        a3 += __shfl_xor(a3, 32, 64);
        den += __shfl_xor(den, 32, 64);
    }
    if (lane < LPR) {
        const float inv = 1.f / (den + 1e-16f);
        const int c0 = cl * 4;
        float v0 = a0 * inv + bias[c0];
        float v1 = a1 * inv + bias[c0 + 1];
        float v2 = a2 * inv + bias[c0 + 2];
        float v3 = a3 * inv + bias[c0 + 3];
        if (RELU) {
            v0 = v0 > 0.f ? v0 : 0.f;
            v1 = v1 > 0.f ? v1 : 0.f;
            v2 = v2 > 0.f ? v2 : 0.f;
            v3 = v3 > 0.f ? v3 : 0.f;
        }
        ushort4 o;
        o.x = f2b(v0);
        o.y = f2b(v1);
        o.z = f2b(v2);
        o.w = f2b(v3);
        *(ushort4*)(outp + (long long)d * OUT + c0) = o;
    }
}

// ---------------- decode: 2 edges per wave, 4 row-loads in flight ----------------
__global__ void decode_k(const int* __restrict__ pei, const int* __restrict__ nei,
                         const unsigned short* __restrict__ z2, float* __restrict__ out) {
    const int wave = threadIdx.x >> 6, lane = threadIdx.x & 63;
    const int base = blockIdx.x * 8 + wave * 2;
    int av[2], bv[2];
    bool ok[2];
#pragma unroll
    for (int k = 0; k < 2; ++k) {
        const int idx = base + k;
        ok[k] = idx < 2 * E_DEC;
        int a = 0, b = 0;
        if (ok[k]) {
            if (idx < E_DEC) {
                a = pei[idx];
                b = pei[E_DEC + idx];
            } else {
                const int j = idx - E_DEC;
                a = nei[j];
                b = nei[E_DEC + j];
            }
        }
        av[k] = a;
        bv[k] = b;
    }
    ushort4 ua[2], ub[2];
#pragma unroll
    for (int k = 0; k < 2; ++k) {
        ua[k] = *(const ushort4*)(z2 + (long long)av[k] * 256 + lane * 4);
        ub[k] = *(const ushort4*)(z2 + (long long)bv[k] * 256 + lane * 4);
    }
#pragma unroll
    for (int k = 0; k < 2; ++k) {
        float s = b2f(ua[k].x) * b2f(ub[k].x) + b2f(ua[k].y) * b2f(ub[k].y) +
                  b2f(ua[k].z) * b2f(ub[k].z) + b2f(ua[k].w) * b2f(ub[k].w);
#pragma unroll
        for (int m = 32; m >= 1; m >>= 1) s += __shfl_xor(s, m, 64);
        if (lane == 0 && ok[k]) out[base + k] = s;
    }
}

extern "C" void kernel_launch(void* const* d_in, const int* in_sizes, int n_in,
                              void* d_out, int out_size, void* d_ws, size_t ws_size,
                              hipStream_t stream) {
    const float* x = (const float*)d_in[0];
    const int* ei = (const int*)d_in[1];
    const int* pei = (const int*)d_in[2];
    const int* nei = (const int*)d_in[3];
    const float* W1 = (const float*)d_in[4];
    const float* as1 = (const float*)d_in[5];
    const float* ad1 = (const float*)d_in[6];
    const float* b1 = (const float*)d_in[7];
    const float* W2 = (const float*)d_in[8];
    const float* as2 = (const float*)d_in[9];
    const float* ad2 = (const float*)d_in[10];
    const float* b2 = (const float*)d_in[11];
    float* out = (float*)d_out;

    // ---- workspace layout ----
    unsigned short* h1 = (unsigned short*)d_ws;              // NN*128
    unsigned short* h2 = h1 + (long long)NN * 128;           // NN*256
    unsigned short* z2 = h2 + (long long)NN * 256;           // NN*256
    unsigned short* z1 = z2 + (long long)NN * 256;           // NN*128
    unsigned short* wp1 = z1 + (long long)NN * 128;          // 128*128
    unsigned short* wp2 = wp1 + 128 * 128;                   // 128*256
    float* als1 = (float*)(wp2 + 128 * 256);                 // NN*H1
    float* ald1 = als1 + NN * H1;
    float* als2 = ald1 + NN * H1;                            // NN*H2
    float* ald2 = als2 + NN * H2;
    int* counts = (int*)(ald2 + NN * H2);                    // NN
    int* start = counts + NN;                                // NN+1
    int* cursor = start + NN + 1;                            // NN
    int* csr = cursor + NN;                                  // ET

    const int NB = (NN + 255) / 256;  // 196

    // ---- CSR build ----
    fillone_k<<<NB, 256, 0, stream>>>(counts, NN);
    hist_k<<<(EE / 4 + 255) / 256, 256, 0, stream>>>(ei, counts);
    scanall_k<<<1, 1024, 0, stream>>>(counts, start, cursor);
    {
        const int nt = EE / 4 + (NN + 3) / 4;
        scatter_k<<<(nt + 255) / 256, 256, 0, stream>>>(ei, cursor, csr);
    }

    // ---- weight packing ----
    packW_k<128><<<(2048 + 255) / 256, 256, 0, stream>>>(W1, wp1);
    packW_k<256><<<(4096 + 255) / 256, 256, 0, stream>>>(W2, wp2);

    // ---- conv1 ----
    mfma_gemm_k<128, H1, 2, true><<<(NN + 63) / 64, 256, 0, stream>>>(
        x, wp1, as1, ad1, h1, als1, ald1);
    gather_k<128, H1, true><<<NN, 64, 0, stream>>>(start, csr, als1, ald1, h1, b1, z1);

    // ---- conv2 ----
    mfma_gemm_k<256, H2, 4, false><<<(NN + 63) / 64, 256, 0, stream>>>(
        z1, wp2, as2, ad2, h2, als2, ald2);
    gather_k<256, H2, false><<<NN, 64, 0, stream>>>(start, csr, als2, ald2, h2, b2, z2);

    // ---- decode ----
    decode_k<<<(2 * E_DEC + 7) / 8, 256, 0, stream>>>(pei, nei, z2, out);
}

// Round 10
// 372.516 us; speedup vs baseline: 1.1986x; 1.1986x over previous
//
#include <hip/hip_runtime.h>
#include <hip/hip_bf16.h>

#define NN 50000
#define EE 800000
#define ET (EE + NN)
#define F_IN 128
#define HID 32
#define H1 4
#define H2 8
#define E_DEC 100000
#define NEG_SLOPE 0.2f

typedef __attribute__((ext_vector_type(8))) short short8;
typedef __attribute__((ext_vector_type(4))) float floatx4;

__device__ __forceinline__ unsigned short f2b(float f) {
    __hip_bfloat16 h = __float2bfloat16(f);
    return *reinterpret_cast<unsigned short*>(&h);
}
__device__ __forceinline__ float b2f(unsigned short u) {
    return __uint_as_float(((unsigned int)u) << 16);
}

// ---------------- fill counts with 1 (self-loop pre-counted) ----------------
__global__ void fillone_k(int* __restrict__ p, int n) {
    int i = blockIdx.x * blockDim.x + threadIdx.x;
    if (i < n) p[i] = 1;
}

// ---------------- CSR build: histogram of dst (real edges only, int4) ----------------
__global__ void hist_k(const int* __restrict__ ei, int* __restrict__ counts) {
    int t = blockIdx.x * blockDim.x + threadIdx.x;
    if (t >= EE / 4) return;
    const int4 d4 = ((const int4*)(ei + EE))[t];
    atomicAdd(&counts[d4.x], 1);
    atomicAdd(&counts[d4.y], 1);
    atomicAdd(&counts[d4.z], 1);
    atomicAdd(&counts[d4.w], 1);
}

// ---------------- hierarchical exclusive scan over counts[NN] ----------------
__global__ void scan1_k(const int* __restrict__ counts, int* __restrict__ bsum) {
    __shared__ int sh[256];
    int t = threadIdx.x;
    int i = blockIdx.x * 256 + t;
    sh[t] = (i < NN) ? counts[i] : 0;
    __syncthreads();
    for (int off = 128; off > 0; off >>= 1) {
        if (t < off) sh[t] += sh[t + off];
        __syncthreads();
    }
    if (t == 0) bsum[blockIdx.x] = sh[0];
}

__global__ void scan2_k(int* __restrict__ bsum, int nb, int* __restrict__ start) {
    __shared__ int sh[256];
    int t = threadIdx.x;
    int v = (t < nb) ? bsum[t] : 0;
    sh[t] = v;
    __syncthreads();
    for (int off = 1; off < 256; off <<= 1) {
        int u = (t >= off) ? sh[t - off] : 0;
        __syncthreads();
        sh[t] += u;
        __syncthreads();
    }
    if (t < nb) bsum[t] = sh[t] - v;  // exclusive block offsets
    if (t == 0) start[NN] = ET;
}

__global__ void scan3_k(const int* __restrict__ counts, const int* __restrict__ bsum,
                        int* __restrict__ start, int* __restrict__ cursor) {
    __shared__ int sh[256];
    int t = threadIdx.x;
    int i = blockIdx.x * 256 + t;
    int c = (i < NN) ? counts[i] : 0;
    sh[t] = c;
    __syncthreads();
    for (int off = 1; off < 256; off <<= 1) {
        int u = (t >= off) ? sh[t - off] : 0;
        __syncthreads();
        sh[t] += u;
        __syncthreads();
    }
    int excl = sh[t] - c + bsum[blockIdx.x];
    if (i < NN) {
        start[i] = excl;
        cursor[i] = excl;
    }
}

// ---------------- scatter: real edges (int4) + self-loops ----------------
__global__ void scatter_k(const int* __restrict__ ei, int* __restrict__ cursor,
                          int* __restrict__ csr) {
    const int NT_E = EE / 4;
    const int t = blockIdx.x * blockDim.x + threadIdx.x;
    if (t < NT_E) {
        const int4 s4 = ((const int4*)ei)[t];
        const int4 d4 = ((const int4*)(ei + EE))[t];
        csr[atomicAdd(&cursor[d4.x], 1)] = s4.x;
        csr[atomicAdd(&cursor[d4.y], 1)] = s4.y;
        csr[atomicAdd(&cursor[d4.z], 1)] = s4.z;
        csr[atomicAdd(&cursor[d4.w], 1)] = s4.w;
    } else {
        const int j = (t - NT_E) * 4;
#pragma unroll
        for (int k = 0; k < 4; ++k) {
            const int n = j + k;
            if (n < NN) csr[atomicAdd(&cursor[n], 1)] = n;
        }
    }
}

// ---------------- pack W into MFMA B-fragment layout ----------------
template <int OUT>
__global__ void packW_k(const float* __restrict__ W, unsigned short* __restrict__ Wp) {
    const int total = (OUT / 16) * 4 * 64;
    int id = blockIdx.x * 256 + threadIdx.x;
    if (id >= total) return;
    const int col = ((id >> 8) << 4) + (id & 15);
    const int k0 = ((id >> 6) & 3) * 32 + ((id >> 4) & 3) * 8;
    ushort4 lo, hi;
    lo.x = f2b(W[(k0 + 0) * OUT + col]);
    lo.y = f2b(W[(k0 + 1) * OUT + col]);
    lo.z = f2b(W[(k0 + 2) * OUT + col]);
    lo.w = f2b(W[(k0 + 3) * OUT + col]);
    hi.x = f2b(W[(k0 + 4) * OUT + col]);
    hi.y = f2b(W[(k0 + 5) * OUT + col]);
    hi.z = f2b(W[(k0 + 6) * OUT + col]);
    hi.w = f2b(W[(k0 + 7) * OUT + col]);
    ((ushort4*)Wp)[id * 2] = lo;
    ((ushort4*)Wp)[id * 2 + 1] = hi;
}

// ---------------- MFMA GEMM + fused al epilogue ----------------
template <int OUT, int H, int CT, bool F32IN>
__global__ void mfma_gemm_k(const void* __restrict__ Xin,
                            const unsigned short* __restrict__ Wp,
                            const float* __restrict__ a_src, const float* __restrict__ a_dst,
                            unsigned short* __restrict__ Hout,
                            float* __restrict__ als, float* __restrict__ ald) {
    const int wave = threadIdx.x >> 6;
    const int lane = threadIdx.x & 63;
    const int quad = lane >> 4;
    const int rl = lane & 15;
    const int r0 = blockIdx.x * 64;
    floatx4 acc[4][CT];
#pragma unroll
    for (int rt = 0; rt < 4; ++rt)
#pragma unroll
        for (int ct = 0; ct < CT; ++ct) acc[rt][ct] = {0.f, 0.f, 0.f, 0.f};

#pragma unroll
    for (int ks = 0; ks < 4; ++ks) {
        short8 a[4];
#pragma unroll
        for (int rt = 0; rt < 4; ++rt) {
            int row = r0 + rt * 16 + rl;
            row = row < NN ? row : NN - 1;
            if (F32IN) {
                const float4* xp =
                    (const float4*)((const float*)Xin + (long long)row * 128 + ks * 32 + quad * 8);
                const float4 v0 = xp[0];
                const float4 v1 = xp[1];
                short8 tt;
                tt[0] = (short)f2b(v0.x);
                tt[1] = (short)f2b(v0.y);
                tt[2] = (short)f2b(v0.z);
                tt[3] = (short)f2b(v0.w);
                tt[4] = (short)f2b(v1.x);
                tt[5] = (short)f2b(v1.y);
                tt[6] = (short)f2b(v1.z);
                tt[7] = (short)f2b(v1.w);
                a[rt] = tt;
            } else {
                a[rt] = *(const short8*)((const unsigned short*)Xin +
                                         (long long)row * 128 + ks * 32 + quad * 8);
            }
        }
#pragma unroll
        for (int ct = 0; ct < CT; ++ct) {
            const int ctg = wave * CT + ct;
            const short8 b = *(const short8*)(Wp + (((ctg * 4 + ks) * 64 + lane) << 3));
#pragma unroll
            for (int rt = 0; rt < 4; ++rt)
                acc[rt][ct] = __builtin_amdgcn_mfma_f32_16x16x32_bf16(a[rt], b, acc[rt][ct], 0, 0, 0);
        }
    }
    // ---- write h ----
#pragma unroll
    for (int rt = 0; rt < 4; ++rt) {
        const int rowbase = r0 + rt * 16 + quad * 4;
#pragma unroll
        for (int ct = 0; ct < CT; ++ct) {
            const int col = (wave * CT + ct) * 16 + rl;
#pragma unroll
            for (int r = 0; r < 4; ++r) {
                const int row = rowbase + r;
                if (row < NN) Hout[(long long)row * OUT + col] = f2b(acc[rt][ct][r]);
            }
        }
    }
    // ---- fused al ----
    float asv[CT], adv[CT];
#pragma unroll
    for (int ct = 0; ct < CT; ++ct) {
        const int col = (wave * CT + ct) * 16 + rl;
        asv[ct] = a_src[col];
        adv[ct] = a_dst[col];
    }
#pragma unroll
    for (int rt = 0; rt < 4; ++rt) {
#pragma unroll
        for (int r = 0; r < 4; ++r) {
            const int row = r0 + rt * 16 + quad * 4 + r;
            float ps[CT / 2], pd[CT / 2];
#pragma unroll
            for (int hh = 0; hh < CT / 2; ++hh) {
                ps[hh] = acc[rt][2 * hh][r] * asv[2 * hh] + acc[rt][2 * hh + 1][r] * asv[2 * hh + 1];
                pd[hh] = acc[rt][2 * hh][r] * adv[2 * hh] + acc[rt][2 * hh + 1][r] * adv[2 * hh + 1];
#pragma unroll
                for (int m = 8; m >= 1; m >>= 1) {
                    ps[hh] += __shfl_xor(ps[hh], m, 64);
                    pd[hh] += __shfl_xor(pd[hh], m, 64);
                }
            }
            if (rl == 0 && row < NN) {
#pragma unroll
                for (int hh = 0; hh < CT / 2; ++hh) {
                    const int hd = wave * (CT / 2) + hh;
                    als[row * H + hd] = ps[hh];
                    ald[row * H + hd] = pd[hh];
                }
            }
        }
    }
}

// ---------------- CSR gather: one wave per node, ushort4/lane, 8/4/1 unroll ----
template <int OUT, int H, bool RELU>
__global__ void gather_k(const int* __restrict__ start, const int* __restrict__ csr,
                         const float* __restrict__ als, const float* __restrict__ ald,
                         const unsigned short* __restrict__ Hin,
                         const float* __restrict__ bias, unsigned short* __restrict__ outp) {
    constexpr int LPR = OUT / 4;           // 64 (OUT=256) or 32 (OUT=128)
    constexpr int EPW = 64 / LPR;          // 1 or 2
    const int d = blockIdx.x;
    const int lane = threadIdx.x;          // blockDim = 64
    const int cl = lane & (LPR - 1);
    const int slot = lane >> (LPR == 64 ? 6 : 5);
    const int hd = cl >> 3;
    const int beg = start[d], end = start[d + 1];
    const float aldd = ald[d * H + hd];
    float a0 = 0.f, a1 = 0.f, a2 = 0.f, a3 = 0.f, den = 0.f;
    int i = beg + slot;
    for (; i + 7 * EPW < end; i += 8 * EPW) {
        int s[8];
        float l[8];
        ushort4 hv[8];
#pragma unroll
        for (int k = 0; k < 8; ++k) s[k] = csr[i + k * EPW];
#pragma unroll
        for (int k = 0; k < 8; ++k) l[k] = als[s[k] * H + hd] + aldd;
#pragma unroll
        for (int k = 0; k < 8; ++k) hv[k] = *(const ushort4*)(Hin + (long long)s[k] * OUT + cl * 4);
#pragma unroll
        for (int k = 0; k < 8; ++k) {
            float lg = l[k] > 0.f ? l[k] : NEG_SLOPE * l[k];
            const float w = __expf(lg);
            den += w;
            a0 += w * b2f(hv[k].x);
            a1 += w * b2f(hv[k].y);
            a2 += w * b2f(hv[k].z);
            a3 += w * b2f(hv[k].w);
        }
    }
    for (; i + 3 * EPW < end; i += 4 * EPW) {
        int s[4];
        float l[4];
        ushort4 hv[4];
#pragma unroll
        for (int k = 0; k < 4; ++k) s[k] = csr[i + k * EPW];
#pragma unroll
        for (int k = 0; k < 4; ++k) l[k] = als[s[k] * H + hd] + aldd;
#pragma unroll
        for (int k = 0; k < 4; ++k) hv[k] = *(const ushort4*)(Hin + (long long)s[k] * OUT + cl * 4);
#pragma unroll
        for (int k = 0; k < 4; ++k) {
            float lg = l[k] > 0.f ? l[k] : NEG_SLOPE * l[k];
            const float w = __expf(lg);
            den += w;
            a0 += w * b2f(hv[k].x);
            a1 += w * b2f(hv[k].y);
            a2 += w * b2f(hv[k].z);
            a3 += w * b2f(hv[k].w);
        }
    }
    for (; i < end; i += EPW) {
        const int s = csr[i];
        float lg = als[s * H + hd] + aldd;
        lg = lg > 0.f ? lg : NEG_SLOPE * lg;
        const float w = __expf(lg);
        const ushort4 hv = *(const ushort4*)(Hin + (long long)s * OUT + cl * 4);
        den += w;
        a0 += w * b2f(hv.x);
        a1 += w * b2f(hv.y);
        a2 += w * b2f(hv.z);
        a3 += w * b2f(hv.w);
    }
    if (EPW == 2) {
        a0 += __shfl_xor(a0, 32, 64);
        a1 += __shfl_xor(a1, 32, 64);
        a2 += __shfl_xor(a2, 32, 64);
        a3 += __shfl_xor(a3, 32, 64);
        den += __shfl_xor(den, 32, 64);
    }
    if (lane < LPR) {
        const float inv = 1.f / (den + 1e-16f);
        const int c0 = cl * 4;
        float v0 = a0 * inv + bias[c0];
        float v1 = a1 * inv + bias[c0 + 1];
        float v2 = a2 * inv + bias[c0 + 2];
        float v3 = a3 * inv + bias[c0 + 3];
        if (RELU) {
            v0 = v0 > 0.f ? v0 : 0.f;
            v1 = v1 > 0.f ? v1 : 0.f;
            v2 = v2 > 0.f ? v2 : 0.f;
            v3 = v3 > 0.f ? v3 : 0.f;
        }
        ushort4 o;
        o.x = f2b(v0);
        o.y = f2b(v1);
        o.z = f2b(v2);
        o.w = f2b(v3);
        *(ushort4*)(outp + (long long)d * OUT + c0) = o;
    }
}

// ---------------- decode: 2 edges per wave, 4 row-loads in flight ----------------
__global__ void decode_k(const int* __restrict__ pei, const int* __restrict__ nei,
                         const unsigned short* __restrict__ z2, float* __restrict__ out) {
    const int wave = threadIdx.x >> 6, lane = threadIdx.x & 63;
    const int base = blockIdx.x * 8 + wave * 2;
    int av[2], bv[2];
    bool ok[2];
#pragma unroll
    for (int k = 0; k < 2; ++k) {
        const int idx = base + k;
        ok[k] = idx < 2 * E_DEC;
        int a = 0, b = 0;
        if (ok[k]) {
            if (idx < E_DEC) {
                a = pei[idx];
                b = pei[E_DEC + idx];
            } else {
                const int j = idx - E_DEC;
                a = nei[j];
                b = nei[E_DEC + j];
            }
        }
        av[k] = a;
        bv[k] = b;
    }
    ushort4 ua[2], ub[2];
#pragma unroll
    for (int k = 0; k < 2; ++k) {
        ua[k] = *(const ushort4*)(z2 + (long long)av[k] * 256 + lane * 4);
        ub[k] = *(const ushort4*)(z2 + (long long)bv[k] * 256 + lane * 4);
    }
#pragma unroll
    for (int k = 0; k < 2; ++k) {
        float s = b2f(ua[k].x) * b2f(ub[k].x) + b2f(ua[k].y) * b2f(ub[k].y) +
                  b2f(ua[k].z) * b2f(ub[k].z) + b2f(ua[k].w) * b2f(ub[k].w);
#pragma unroll
        for (int m = 32; m >= 1; m >>= 1) s += __shfl_xor(s, m, 64);
        if (lane == 0 && ok[k]) out[base + k] = s;
    }
}

extern "C" void kernel_launch(void* const* d_in, const int* in_sizes, int n_in,
                              void* d_out, int out_size, void* d_ws, size_t ws_size,
                              hipStream_t stream) {
    const float* x = (const float*)d_in[0];
    const int* ei = (const int*)d_in[1];
    const int* pei = (const int*)d_in[2];
    const int* nei = (const int*)d_in[3];
    const float* W1 = (const float*)d_in[4];
    const float* as1 = (const float*)d_in[5];
    const float* ad1 = (const float*)d_in[6];
    const float* b1 = (const float*)d_in[7];
    const float* W2 = (const float*)d_in[8];
    const float* as2 = (const float*)d_in[9];
    const float* ad2 = (const float*)d_in[10];
    const float* b2 = (const float*)d_in[11];
    float* out = (float*)d_out;

    // ---- workspace layout ----
    unsigned short* h1 = (unsigned short*)d_ws;              // NN*128
    unsigned short* h2 = h1 + (long long)NN * 128;           // NN*256
    unsigned short* z2 = h2 + (long long)NN * 256;           // NN*256
    unsigned short* z1 = z2 + (long long)NN * 256;           // NN*128
    unsigned short* wp1 = z1 + (long long)NN * 128;          // 128*128
    unsigned short* wp2 = wp1 + 128 * 128;                   // 128*256
    float* als1 = (float*)(wp2 + 128 * 256);                 // NN*H1
    float* ald1 = als1 + NN * H1;
    float* als2 = ald1 + NN * H1;                            // NN*H2
    float* ald2 = als2 + NN * H2;
    int* counts = (int*)(ald2 + NN * H2);                    // NN
    int* start = counts + NN;                                // NN+1
    int* cursor = start + NN + 1;                            // NN
    int* bsum = cursor + NN;                                 // 256
    int* csr = bsum + 256;                                   // ET

    const int NB = (NN + 255) / 256;  // 196

    // ---- CSR build ----
    fillone_k<<<NB, 256, 0, stream>>>(counts, NN);
    hist_k<<<(EE / 4 + 255) / 256, 256, 0, stream>>>(ei, counts);
    scan1_k<<<NB, 256, 0, stream>>>(counts, bsum);
    scan2_k<<<1, 256, 0, stream>>>(bsum, NB, start);
    scan3_k<<<NB, 256, 0, stream>>>(counts, bsum, start, cursor);
    {
        const int nt = EE / 4 + (NN + 3) / 4;
        scatter_k<<<(nt + 255) / 256, 256, 0, stream>>>(ei, cursor, csr);
    }

    // ---- weight packing ----
    packW_k<128><<<(2048 + 255) / 256, 256, 0, stream>>>(W1, wp1);
    packW_k<256><<<(4096 + 255) / 256, 256, 0, stream>>>(W2, wp2);

    // ---- conv1 ----
    mfma_gemm_k<128, H1, 2, true><<<(NN + 63) / 64, 256, 0, stream>>>(
        x, wp1, as1, ad1, h1, als1, ald1);
    gather_k<128, H1, true><<<NN, 64, 0, stream>>>(start, csr, als1, ald1, h1, b1, z1);

    // ---- conv2 ----
    mfma_gemm_k<256, H2, 4, false><<<(NN + 63) / 64, 256, 0, stream>>>(
        z1, wp2, as2, ad2, h2, als2, ald2);
    gather_k<256, H2, false><<<NN, 64, 0, stream>>>(start, csr, als2, ald2, h2, b2, z2);

    // ---- decode ----
    decode_k<<<(2 * E_DEC + 7) / 8, 256, 0, stream>>>(pei, nei, z2, out);
}